// Round 1
// baseline (476.773 us; speedup 1.0000x reference)
//
#include <hip/hip_runtime.h>
#include <math.h>

#define NB 32
#define NC 192
#define NCR 48
#define NT 16
#define NHW 784
#define NHW4 196                 // 784 floats = 196 float4
#define GB 8                     // batches per pipeline group
#define NGRP (NB / GB)           // 4 groups; group x-slice = 77 MB << 256 MB L3
#define SLABS_G (GB * NC * NT)   // 24576 (b,c,t) wave-slabs per group
#define BLKA (SLABS_G / 4)       // 6144 A-blocks per group (4 waves/block)
#define BLKC (GB * NC)           // 1536 C-blocks per group

// native clang vector type for nontemporal builtins
typedef float vfloat4 __attribute__((ext_vector_type(4)));

// Fused pipeline kernel: one dispatch carries the A-part (spatial means) for
// group a_group AND the C-part (weighted output sum) for group c_group.
//   A-part: reads x[a_group] from HBM with CACHEABLE loads -> populates L3.
//   C-part: re-reads x[c_group] (streamed by the PREVIOUS dispatch's A-part,
//           77 MB, guaranteed L3-resident) with CACHEABLE loads -> L3 hits,
//           overlapped with the A-part's HBM stream.
// Block mapping when mixed: every 5th block is a C-block (7680 = 1536*5), so
// both streams stay active across the whole dispatch.
__global__ __launch_bounds__(256) void pipe_kernel(
    const float* __restrict__ x, float* __restrict__ sq,
    const float* __restrict__ coef, float* __restrict__ out,
    const int a_group, const int c_group, const int mixed) {
  int ai = -1, ci = -1;
  {
    const int bx = (int)blockIdx.x;
    if (mixed) {
      if (bx % 5 == 0) ci = bx / 5;
      else             ai = bx - bx / 5 - 1;      // bijective onto [0, BLKA)
    } else if (a_group >= 0) {
      ai = bx;
    } else {
      ci = bx;
    }
  }

  if (ai >= 0) {
    // ---- A-part: spatial mean over H*W for 4 (b,c,t) slabs (1 wave each) ----
    const int wave = threadIdx.x >> 6;
    const int lane = threadIdx.x & 63;
    const int slab = a_group * SLABS_G + ai * 4 + wave;  // absolute (b*NC+c)*NT+t
    const float4* x4 = (const float4*)x + (size_t)slab * NHW4;

    float s = 0.f;
    float4 v;
    v = x4[lane];        s += v.x + v.y + v.z + v.w;
    v = x4[lane + 64];   s += v.x + v.y + v.z + v.w;
    v = x4[lane + 128];  s += v.x + v.y + v.z + v.w;
    if (lane < 4) { v = x4[lane + 192]; s += v.x + v.y + v.z + v.w; }

    #pragma unroll
    for (int off = 32; off > 0; off >>= 1) s += __shfl_down(s, off);
    if (lane == 0) sq[slab] = s * (1.0f / (float)NHW);
  } else {
    // ---- C-part: out[b,c,:,:] = sum_t x[b,c,t,:,:] * coef[b,c,t] ----
    __shared__ float cf[NT];
    const int slab = c_group * BLKC + ci;                // absolute b*NC + c
    const int tid = threadIdx.x;

    if (tid < NT) cf[tid] = coef[slab * NT + tid];
    __syncthreads();

    if (tid < NHW4) {
      // CACHEABLE loads on purpose: this 77 MB group slice is L3-resident
      // from the previous dispatch's A-part; we want the hit.
      const vfloat4* x4 = (const vfloat4*)x + (size_t)slab * NT * NHW4 + tid;
      vfloat4 acc = {0.f, 0.f, 0.f, 0.f};
      #pragma unroll
      for (int t = 0; t < NT; ++t) acc += x4[(size_t)t * NHW4] * cf[t];
      // out is write-once, dead after: keep the store nontemporal so it
      // doesn't evict the next group's A-populated lines.
      __builtin_nontemporal_store(acc, (vfloat4*)out + (size_t)slab * NHW4 + tid);
    }
  }
}

// Per-group MLP: h = relu(w1 @ s + b1); attn = sigmoid(w2 @ h + b2);
// coef = 0.5*attn + 0.5*ms_weight[t]. One 192-thread block per (b,t); 128
// blocks per group (tiny, ~3 us).
__global__ __launch_bounds__(192) void attn_coef_kernel(
    const float* __restrict__ sq, const float* __restrict__ w1,
    const float* __restrict__ b1, const float* __restrict__ w2,
    const float* __restrict__ b2, const float* __restrict__ sw,
    float* __restrict__ coef, const int g) {
  __shared__ float s[NC];
  __shared__ float h[NCR];
  const int b = g * GB + ((int)blockIdx.x >> 4);
  const int t = (int)blockIdx.x & 15;
  const int tid = threadIdx.x;

  s[tid] = sq[((b * NC + tid) * NT) + t];
  __syncthreads();

  if (tid < NCR) {
    float acc = b1[tid];
    const float* wr = w1 + tid * NC;
    #pragma unroll 8
    for (int c = 0; c < NC; ++c) acc += wr[c] * s[c];
    h[tid] = fmaxf(acc, 0.f);
  }
  __syncthreads();

  float acc = b2[tid];
  const float* wr = w2 + tid * NCR;
  #pragma unroll 8
  for (int o = 0; o < NCR; ++o) acc += wr[o] * h[o];
  const float attn = 1.f / (1.f + expf(-acc));

  // softmax over the 3 scale weights (redundant per-thread; trivial)
  const float s0 = sw[0], s1 = sw[1], s2 = sw[2];
  const float m = fmaxf(s0, fmaxf(s1, s2));
  const float e0 = expf(s0 - m), e1 = expf(s1 - m), e2 = expf(s2 - m);
  const float inv = 1.f / (e0 + e1 + e2);
  float ms = e2 * inv * (1.f / 16.f);            // overall mean term
  if (t >= NT / 2) ms += e1 * inv * (1.f / 8.f); // mid mean term
  if (t == NT - 1) ms += e0 * inv;               // recent term

  coef[(b * NC + tid) * NT + t] = 0.5f * attn + 0.5f * ms;
}

extern "C" void kernel_launch(void* const* d_in, const int* in_sizes, int n_in,
                              void* d_out, int out_size, void* d_ws, size_t ws_size,
                              hipStream_t stream) {
  const float* x  = (const float*)d_in[0];
  const float* w1 = (const float*)d_in[1];
  const float* b1 = (const float*)d_in[2];
  const float* w2 = (const float*)d_in[3];
  const float* b2 = (const float*)d_in[4];
  const float* sw = (const float*)d_in[5];
  float* out = (float*)d_out;

  float* sq   = (float*)d_ws;            // NB*NC*NT floats = 384 KiB
  float* coef = sq + NB * NC * NT;       // NB*NC*NT floats = 384 KiB

  // Software pipeline over 4 batch-groups of 8:
  //   P0: A(0)            -> means for group 0 stream in, land in L3
  //   B0: coef(0)
  //   Pg: C(g-1) + A(g)   -> C reads L3-resident slice, A streams next slice
  //   Bg: coef(g)
  //   P4: C(3)
  pipe_kernel<<<BLKA, 256, 0, stream>>>(x, sq, coef, out, 0, -1, 0);
  attn_coef_kernel<<<GB * NT, 192, 0, stream>>>(sq, w1, b1, w2, b2, sw, coef, 0);
  for (int g = 1; g < NGRP; ++g) {
    pipe_kernel<<<BLKA + BLKC, 256, 0, stream>>>(x, sq, coef, out, g, g - 1, 1);
    attn_coef_kernel<<<GB * NT, 192, 0, stream>>>(sq, w1, b1, w2, b2, sw, coef, g);
  }
  pipe_kernel<<<BLKC, 256, 0, stream>>>(x, sq, coef, out, -1, NGRP - 1, 0);
}